// Round 11
// baseline (121.910 us; speedup 1.0000x reference)
//
#include <hip/hip_runtime.h>
#include <math.h>

#define EPS_BN 1e-5f

typedef __attribute__((ext_vector_type(8))) short short8;
typedef __attribute__((ext_vector_type(4))) float f32x4;
typedef __attribute__((ext_vector_type(4))) unsigned int uint4v;

__device__ __forceinline__ unsigned short f2bf(float f) {
    unsigned int u = __float_as_uint(f);
    u = (u + 0x7fffu + ((u >> 16) & 1u)) >> 16;
    return (unsigned short)u;
}
__device__ __forceinline__ float bf2f(unsigned short s) {
    return __uint_as_float(((unsigned int)s) << 16);
}
__device__ __forceinline__ float elu1(float y) { return y > 0.f ? y : expm1f(y); }
__device__ __forceinline__ float warp_sum(float v) {
    for (int off = 32; off > 0; off >>= 1) v += __shfl_down(v, off);
    return v;
}

// ---------------- workspace layout ----------------
#define UW1 0        // [10][32][64]   20480
#define UW2 20480    // [10][64][32]   20480
#define UW3 40960    // [10][128][64]  81920
#define UW4 122880   // [10][224][128] 286720 -> ends 409600 ush (819200 B)
#define BB1 0
#define BB2 32
#define BB3 96
#define BB4 224
#define Z1G_U 9192320   // z1  [128][330][32]
#define Z2G_U 10544000  // z2  [128][107][64]
#define Z3G_U 11420544  // z3  [128][44][136]

#define RS_ZB 36

// ---------------------------------------------------------------------------
// kprep: BN-folded bf16 weight prep + fused biases only (transpose removed —
// ks1 now transposes in-block). 1602 blocks.
// ---------------------------------------------------------------------------
__global__ __launch_bounds__(256) void kprep(
    const float* __restrict__ w_time, const float* __restrict__ b_time,
    const float* __restrict__ w_spat,
    const float* __restrict__ w2, const float* __restrict__ w3,
    const float* __restrict__ w4,
    const float* __restrict__ g1, const float* __restrict__ be1,
    const float* __restrict__ m1, const float* __restrict__ v1,
    const float* __restrict__ g2, const float* __restrict__ be2,
    const float* __restrict__ m2, const float* __restrict__ v2,
    const float* __restrict__ g3, const float* __restrict__ be3,
    const float* __restrict__ m3, const float* __restrict__ v3,
    const float* __restrict__ g4, const float* __restrict__ be4,
    const float* __restrict__ m4, const float* __restrict__ v4,
    unsigned short* __restrict__ wsz, float* __restrict__ biasf) {
    int idx = blockIdx.x * 256 + threadIdx.x;
    if (idx < 20480) {                       // Wpk1 [10][32][64]
        int k = idx >> 11, g = (idx >> 6) & 31, c = idx & 63;
        float val = 0.f;
        if (g < 25) {
            float s = 0.f;
#pragma unroll
            for (int f = 0; f < 25; ++f)
                s = fmaf(w_spat[g * 1600 + f * 64 + c], w_time[f * 10 + k], s);
            val = s * (g1[g] * rsqrtf(v1[g] + EPS_BN));
        }
        wsz[UW1 + idx] = f2bf(val);
    } else if (idx < 40960) {                // Wpk2 [10][64][32]
        int j = idx - 20480;
        int k = j >> 11, g = (j >> 5) & 63, c = j & 31;
        float val = 0.f;
        if (g < 50 && c < 25)
            val = w2[(g * 25 + c) * 10 + k] * (g2[g] * rsqrtf(v2[g] + EPS_BN));
        wsz[UW2 + j] = f2bf(val);
    } else if (idx < 122880) {               // Wpk3 [10][128][64]
        int j = idx - 40960;
        int k = j >> 13, g = (j >> 6) & 127, c = j & 63;
        float val = 0.f;
        if (g < 100 && c < 50)
            val = w3[(g * 50 + c) * 10 + k] * (g3[g] * rsqrtf(v3[g] + EPS_BN));
        wsz[UW3 + j] = f2bf(val);
    } else if (idx < 409600) {               // Wpk4 [10][224][128]
        int j = idx - 122880;
        int k = j / 28672, r = j % 28672, g = r >> 7, c = r & 127;
        float val = 0.f;
        if (g < 200 && c < 100)
            val = w4[(g * 100 + c) * 10 + k] * (g4[g] * rsqrtf(v4[g] + EPS_BN));
        wsz[UW4 + j] = f2bf(val);
    } else if (idx < 410048) {               // biases
        int j = idx - 409600;
        if (j < 32) {
            int g = j; float val = 0.f;
            if (g < 25) {
                float beff = 0.f;
                for (int f = 0; f < 25; ++f) {
                    float a = 0.f;
                    for (int c = 0; c < 64; ++c) a += w_spat[g * 1600 + f * 64 + c];
                    beff = fmaf(a, b_time[f], beff);
                }
                float sc = g1[g] * rsqrtf(v1[g] + EPS_BN);
                val = be1[g] - m1[g] * sc + beff * sc;
            }
            biasf[BB1 + g] = val;
        } else if (j < 96) {
            int g = j - 32; float val = 0.f;
            if (g < 50) { float sc = g2[g] * rsqrtf(v2[g] + EPS_BN); val = be2[g] - m2[g] * sc; }
            biasf[BB2 + g] = val;
        } else if (j < 224) {
            int g = j - 96; float val = 0.f;
            if (g < 100) { float sc = g3[g] * rsqrtf(v3[g] + EPS_BN); val = be3[g] - m3[g] * sc; }
            biasf[BB3 + g] = val;
        } else {
            int g = j - 224; float val = 0.f;
            if (g < 200) { float sc = g4[g] * rsqrtf(v4[g] + EPS_BN); val = be4[g] - m4[g] * sc; }
            biasf[BB4 + g] = val;
        }
    }
}

// ---------------------------------------------------------------------------
// conv_job: one wave-job of MFMA conv(K=10)+bias+ELU+pool3 (validated rounds
// 7-10; tl0=0, KPRE register-hoisted weights).
// ---------------------------------------------------------------------------
template<int CPAD, int RS, int SP, int TT, int TPC, int NCHUNK, int JMAX,
         int GPAD, int TPOOL, int GSTORE, int NGV, int OUT_RS, bool OUT_F32,
         int KPRE>
__device__ __forceinline__ void conv_job(
    const unsigned short* xT, const unsigned short* __restrict__ wpk,
    const float* __restrict__ bias,
    unsigned short* zout, float* zoutf, unsigned short* zbw,
    int lane, int gbi, int po0) {
    const int lm = lane & 15, h8 = lane >> 4;
    const int gloc = lane & 31, hh = lane >> 5;

    f32x4 acc[TT][2];
#pragma unroll
    for (int i = 0; i < TT; ++i) {
        acc[i][0] = (f32x4){0.f, 0.f, 0.f, 0.f};
        acc[i][1] = (f32x4){0.f, 0.f, 0.f, 0.f};
    }

    const int abase = lm * RS + h8 * 8;
    const unsigned short* wp = wpk + (gbi * 32 + lm) * CPAD + h8 * 8;
#pragma unroll
    for (int ph = 0; ph < 10 / KPRE; ++ph) {
        short8 w0r[KPRE][SP], w1r[KPRE][SP];
#pragma unroll
        for (int kk = 0; kk < KPRE; ++kk) {
            const int k = ph * KPRE + kk;
#pragma unroll
            for (int s = 0; s < SP; ++s) {
                w0r[kk][s] = *(const short8*)(wp + k * (GPAD * CPAD) + s * 32);
                w1r[kk][s] = *(const short8*)(wp + k * (GPAD * CPAD) + 16 * CPAD + s * 32);
            }
        }
#pragma unroll
        for (int kk = 0; kk < KPRE; ++kk) {
            const int k = ph * KPRE + kk;
#pragma unroll
            for (int s = 0; s < SP; ++s) {
#pragma unroll
                for (int tt = 0; tt < TT; ++tt) {
                    short8 a = *(const short8*)&xT[abase + (tt * 16 + k) * RS + s * 32];
                    acc[tt][0] = __builtin_amdgcn_mfma_f32_16x16x32_bf16(
                        a, w0r[kk][s], acc[tt][0], 0, 0, 0);
                    acc[tt][1] = __builtin_amdgcn_mfma_f32_16x16x32_bf16(
                        a, w1r[kk][s], acc[tt][1], 0, 0, 0);
                }
            }
        }
    }

    const float bv0 = bias[gbi * 32 + lm];
    const float bv1 = bias[gbi * 32 + 16 + lm];
#pragma unroll
    for (int ch = 0; ch < NCHUNK; ++ch) {
#pragma unroll
        for (int ti = 0; ti < TPC; ++ti) {
            int ttg = ch * TPC + ti;
#pragma unroll
            for (int r = 0; r < 4; ++r) {
                float v0 = elu1(acc[ttg][0][r] + bv0);
                float v1 = elu1(acc[ttg][1][r] + bv1);
                int row = ti * 16 + 4 * h8 + r;
                zbw[row * RS_ZB + lm] = f2bf(v0);
                zbw[row * RS_ZB + 16 + lm] = f2bf(v1);
            }
        }
#pragma unroll
        for (int j = 0; j < JMAX; ++j) {
            int po = hh + 2 * j;
            if (3 * po + 2 < TPC * 16) {
                float q0 = bf2f(zbw[(3 * po) * RS_ZB + gloc]);
                float q1 = bf2f(zbw[(3 * po + 1) * RS_ZB + gloc]);
                float q2 = bf2f(zbw[(3 * po + 2) * RS_ZB + gloc]);
                float mx = fmaxf(q0, fmaxf(q1, q2));
                int poa = po0 + ch * 16 + po;
                int ga = gbi * 32 + gloc;
                if (poa < TPOOL && ga < GSTORE) {
                    if constexpr (OUT_F32)
                        zoutf[poa * OUT_RS + ga] = mx;
                    else
                        zout[poa * OUT_RS + ga] =
                            (ga < NGV) ? f2bf(mx) : (unsigned short)0;
                }
            }
        }
    }
}

// ---------------------------------------------------------------------------
// ks1: stage1 with coalesced IN-BLOCK transpose. grid (128, 21), 64 threads.
// Pass A: lanes (c = idx>>4, q = idx&15) read float4 x[b][c][t0+4q..] —
//   16 lanes cover 256 contiguous bytes per channel (coalesced), store to
//   padded f32 LDS tile trf[64][65].
// Pass B: repack to bf16 xT[64][72] (reads 2-way bank alias = free; writes
//   conflict-free).
// ---------------------------------------------------------------------------
__global__ __launch_bounds__(64) void ks1(
    const float* __restrict__ x,
    const unsigned short* __restrict__ wsu, const float* __restrict__ biasf,
    unsigned short* __restrict__ wsz) {
    __shared__ __align__(16) float trf[64 * 65];
    __shared__ __align__(16) unsigned short xT[64 * 72];
    __shared__ __align__(16) unsigned short zb[48 * RS_ZB];
    const int b = blockIdx.x, tci = blockIdx.y, lane = threadIdx.x;
    const int t0 = tci * 48;
    const float* xb = x + b * 64000;
    for (int idx = lane; idx < 1024; idx += 64) {
        int c = idx >> 4, q = idx & 15;
        int tg = t0 + 4 * q;
        float4 v = {0.f, 0.f, 0.f, 0.f};
        if (tg + 4 <= 1000) {
            v = *(const float4*)(xb + c * 1000 + tg);
        } else if (tg < 1000) {
            float* pv = (float*)&v;
#pragma unroll
            for (int e = 0; e < 4; ++e)
                if (tg + e < 1000) pv[e] = xb[c * 1000 + tg + e];
        }
        trf[c * 65 + 4 * q]     = v.x;
        trf[c * 65 + 4 * q + 1] = v.y;
        trf[c * 65 + 4 * q + 2] = v.z;
        trf[c * 65 + 4 * q + 3] = v.w;
    }
    __syncthreads();
    for (int idx = lane; idx < 2048; idx += 64) {
        int tl = idx >> 5, cp = idx & 31;
        unsigned int pk = (unsigned int)f2bf(trf[(2 * cp) * 65 + tl]) |
                          ((unsigned int)f2bf(trf[(2 * cp + 1) * 65 + tl]) << 16);
        *(unsigned int*)&xT[tl * 72 + 2 * cp] = pk;
    }
    __syncthreads();
    conv_job<64, 72, 2, 3, 3, 1, 8, 32, 330, 32, 25, 32, false, 5>(
        xT, wsu + UW1, biasf + BB1,
        wsz + Z1G_U + b * 330 * 32, nullptr, zb, lane, 0, tci * 16);
}

// ---------------------------------------------------------------------------
// ks2: stage2. grid (128, 14): gbi = y/7, tci = y%7.
// ---------------------------------------------------------------------------
__global__ __launch_bounds__(64) void ks2(
    const unsigned short* __restrict__ wsu, const float* __restrict__ biasf,
    unsigned short* __restrict__ wsz) {
    __shared__ __align__(16) unsigned short xT[64 * 40];
    __shared__ __align__(16) unsigned short zb[48 * RS_ZB];
    const int b = blockIdx.x, y = blockIdx.y, lane = threadIdx.x;
    const int gbi = y / 7, tci = y % 7, t0b = tci * 48;
    const unsigned short* z1g = wsz + Z1G_U + b * 330 * 32;
    for (int idx = lane; idx < 256; idx += 64) {
        int r = idx >> 2, q = idx & 3;
        uint4v v = {0u, 0u, 0u, 0u};
        if (t0b + r < 330) v = *(const uint4v*)&z1g[(t0b + r) * 32 + 8 * q];
        *(uint4v*)&xT[r * 40 + 8 * q] = v;
    }
    __syncthreads();
    conv_job<32, 40, 1, 3, 3, 1, 8, 64, 107, 64, 50, 64, false, 5>(
        xT, wsu + UW2, biasf + BB2,
        wsz + Z2G_U + b * 107 * 64, nullptr, zb, lane, gbi, tci * 16);
}

// ---------------------------------------------------------------------------
// ks3: stage3. grid (128, 8): gbi = y/2, tci = y%2.
// ---------------------------------------------------------------------------
__global__ __launch_bounds__(64) void ks3(
    const unsigned short* __restrict__ wsu, const float* __restrict__ biasf,
    unsigned short* __restrict__ wsz) {
    __shared__ __align__(16) unsigned short z2t[64 * 72];
    __shared__ __align__(16) unsigned short zb[48 * RS_ZB];
    const int b = blockIdx.x, y = blockIdx.y, lane = threadIdx.x;
    const int gbi = y / 2, tci = y % 2, t0b = tci * 48;
    const unsigned short* z2g = wsz + Z2G_U + b * 107 * 64;
    for (int idx = lane; idx < 512; idx += 64) {
        int r = idx >> 3, q = idx & 7;
        uint4v v = {0u, 0u, 0u, 0u};
        if (t0b + r < 107) v = *(const uint4v*)&z2g[(t0b + r) * 64 + 8 * q];
        *(uint4v*)&z2t[r * 72 + 8 * q] = v;
    }
    __syncthreads();
    conv_job<64, 72, 2, 3, 3, 1, 8, 128, 32, 128, 100, 136, false, 5>(
        z2t, wsu + UW3, biasf + BB3,
        wsz + Z3G_U + b * 44 * 136, nullptr, zb, lane, gbi, tci * 16);
}

// ---------------------------------------------------------------------------
// ks4h: stage4 + head. 128 blocks x 448 threads (7 waves; wave wv = gbi).
// z4 stays in LDS; head runs after __syncthreads.
// ---------------------------------------------------------------------------
__global__ __launch_bounds__(448) void ks4h(
    const unsigned short* __restrict__ wsu, const float* __restrict__ biasf,
    const unsigned short* __restrict__ wsz,
    const float* __restrict__ w_cls, const float* __restrict__ b_cls,
    const int* __restrict__ cid,
    const float* __restrict__ hW1, const float* __restrict__ hb1,
    const float* __restrict__ hW2, const float* __restrict__ hb2,
    const float* __restrict__ hg, const float* __restrict__ hbe,
    const float* __restrict__ hm, const float* __restrict__ hv,
    float* __restrict__ out) {
    __shared__ __align__(16) unsigned short z3t[44 * 136];   // 11968 B
    __shared__ __align__(16) unsigned short zb[7 * 32 * RS_ZB];
    __shared__ float z4f[1400];
    __shared__ float feats[4];
    __shared__ float h1s[512];
    const int b = blockIdx.x, t = threadIdx.x;
    const int lane = t & 63, wv = t >> 6;
    const unsigned short* z3g = wsz + Z3G_U + b * 44 * 136;
    for (int idx = t; idx < 748; idx += 448) {
        int r = idx / 17, q = idx % 17;
        uint4v v = {0u, 0u, 0u, 0u};
        if (r < 32) v = *(const uint4v*)&z3g[r * 136 + 8 * q];
        *(uint4v*)&z3t[r * 136 + 8 * q] = v;
    }
    __syncthreads();

    conv_job<128, 136, 4, 2, 2, 1, 4, 224, 7, 200, 200, 200, true, 5>(
        z3t, wsu + UW4, biasf + BB4,
        nullptr, z4f, zb + wv * (32 * RS_ZB), lane, wv, 0);
    __syncthreads();

    // ---- head ----
    if (wv < 4) {
        float p = 0.f;
        for (int i = lane; i < 1400; i += 64) {
            int po = i / 200, g = i - po * 200;
            p = fmaf(z4f[i], w_cls[wv * 1400 + g * 7 + po], p);
        }
        p = warp_sum(p);
        if (lane == 0) feats[wv] = p + b_cls[wv];
    }
    __syncthreads();

    const int c = cid[b];
    const float f0 = feats[0], f1 = feats[1], f2 = feats[2], f3 = feats[3];
    for (int h = t; h < 512; h += 448) {
        const float* w1 = &hW1[(c * 512 + h) * 4];
        float v = f0 * w1[0] + f1 * w1[1] + f2 * w1[2] + f3 * w1[3] + hb1[c * 512 + h];
        float sc = hg[c * 512 + h] * rsqrtf(hv[c * 512 + h] + EPS_BN);
        v = (v - hm[c * 512 + h]) * sc + hbe[c * 512 + h];
        h1s[h] = fmaxf(v, 0.f);
    }
    __syncthreads();
    if (wv < 4) {
        float p = 0.f;
        for (int i = lane; i < 512; i += 64)
            p = fmaf(h1s[i], hW2[(c * 4 + wv) * 512 + i], p);
        p = warp_sum(p);
        if (lane == 0) out[b * 4 + wv] = p + hb2[c * 4 + wv];
    }
}

// ---------------------------------------------------------------------------
extern "C" void kernel_launch(void* const* d_in, const int* in_sizes, int n_in,
                              void* d_out, int out_size, void* d_ws, size_t ws_size,
                              hipStream_t stream) {
    const float* x      = (const float*)d_in[0];
    const int*   cid    = (const int*)d_in[1];
    const float* w_time = (const float*)d_in[2];
    const float* b_time = (const float*)d_in[3];
    const float* w_spat = (const float*)d_in[4];
    const float* w2     = (const float*)d_in[5];
    const float* w3     = (const float*)d_in[6];
    const float* w4     = (const float*)d_in[7];
    const float* w_cls  = (const float*)d_in[8];
    const float* b_cls  = (const float*)d_in[9];
    const float* hW1    = (const float*)d_in[10];
    const float* hb1    = (const float*)d_in[11];
    const float* hW2    = (const float*)d_in[12];
    const float* hb2    = (const float*)d_in[13];
    const float* hg     = (const float*)d_in[14];
    const float* hbe    = (const float*)d_in[15];
    const float* hm     = (const float*)d_in[16];
    const float* hv     = (const float*)d_in[17];
    const float* g1  = (const float*)d_in[18];
    const float* be1 = (const float*)d_in[19];
    const float* m1  = (const float*)d_in[20];
    const float* v1  = (const float*)d_in[21];
    const float* g2  = (const float*)d_in[22];
    const float* be2 = (const float*)d_in[23];
    const float* m2  = (const float*)d_in[24];
    const float* v2  = (const float*)d_in[25];
    const float* g3  = (const float*)d_in[26];
    const float* be3 = (const float*)d_in[27];
    const float* m3  = (const float*)d_in[28];
    const float* v3  = (const float*)d_in[29];
    const float* g4  = (const float*)d_in[30];
    const float* be4 = (const float*)d_in[31];
    const float* m4  = (const float*)d_in[32];
    const float* v4  = (const float*)d_in[33];

    unsigned short* wsz = (unsigned short*)d_ws;
    float* biasf = (float*)((char*)d_ws + 819200);
    float* out = (float*)d_out;

    kprep<<<1602, 256, 0, stream>>>(w_time, b_time, w_spat, w2, w3, w4,
                                    g1, be1, m1, v1, g2, be2, m2, v2,
                                    g3, be3, m3, v3, g4, be4, m4, v4,
                                    wsz, biasf);

    ks1<<<dim3(128, 21), 64, 0, stream>>>(x, wsz, biasf, wsz);
    ks2<<<dim3(128, 14), 64, 0, stream>>>(wsz, biasf, wsz);
    ks3<<<dim3(128, 8), 64, 0, stream>>>(wsz, biasf, wsz);
    ks4h<<<128, 448, 0, stream>>>(wsz, biasf, wsz, w_cls, b_cls, cid,
                                  hW1, hb1, hW2, hb2, hg, hbe, hm, hv, out);
}

// Round 12
// 94.116 us; speedup vs baseline: 1.2953x; 1.2953x over previous
//
#include <hip/hip_runtime.h>
#include <math.h>

#define EPS_BN 1e-5f

typedef __attribute__((ext_vector_type(8))) short short8;
typedef __attribute__((ext_vector_type(4))) float f32x4;
typedef __attribute__((ext_vector_type(4))) unsigned int uint4v;

__device__ __forceinline__ unsigned short f2bf(float f) {
    unsigned int u = __float_as_uint(f);
    u = (u + 0x7fffu + ((u >> 16) & 1u)) >> 16;
    return (unsigned short)u;
}
__device__ __forceinline__ float bf2f(unsigned short s) {
    return __uint_as_float(((unsigned int)s) << 16);
}
__device__ __forceinline__ float elu1(float y) { return y > 0.f ? y : expm1f(y); }
__device__ __forceinline__ float warp_sum(float v) {
    for (int off = 32; off > 0; off >>= 1) v += __shfl_down(v, off);
    return v;
}

// ---------------- workspace layout ----------------
#define UW1 0        // [10][32][64]   20480
#define UW2 20480    // [10][64][32]   20480
#define UW3 40960    // [10][128][64]  81920
#define UW4 122880   // [10][224][128] 286720 -> ends 409600 ush (819200 B)
#define BB1 0
#define BB2 32
#define BB3 96
#define BB4 224
#define XTG_U 410496    // xT  [128][1072][64]  (byte 820992)
#define Z1G_U 9192320   // z1  [128][330][32]
#define Z2G_U 10544000  // z2  [128][107][64]
#define Z3G_U 11420544  // z3  [128][44][136]
#define Z4G_BYTE 24372992  // z4 f32 [128][7][200]

#define NPREP 1602
#define RS2 20          // zb stride for 16-g jobs (16 cols + 4 pad)
#define ZBW (48 * RS2)  // 960 ush = 1920 B per wave

// ---------------------------------------------------------------------------
// kprep_tr: blocks [0,NPREP) = BN-folded bf16 weight prep (verified round 3);
//           blocks >= NPREP  = tiled x transpose -> xT bf16 [b][t][c]
//           (coalesced reads, padded-LDS bounce, coalesced writes). R7-exact.
// ---------------------------------------------------------------------------
__global__ __launch_bounds__(256) void kprep_tr(
    const float* __restrict__ x,
    const float* __restrict__ w_time, const float* __restrict__ b_time,
    const float* __restrict__ w_spat,
    const float* __restrict__ w2, const float* __restrict__ w3,
    const float* __restrict__ w4,
    const float* __restrict__ g1, const float* __restrict__ be1,
    const float* __restrict__ m1, const float* __restrict__ v1,
    const float* __restrict__ g2, const float* __restrict__ be2,
    const float* __restrict__ m2, const float* __restrict__ v2,
    const float* __restrict__ g3, const float* __restrict__ be3,
    const float* __restrict__ m3, const float* __restrict__ v3,
    const float* __restrict__ g4, const float* __restrict__ be4,
    const float* __restrict__ m4, const float* __restrict__ v4,
    unsigned short* __restrict__ wsz, float* __restrict__ biasf) {
    __shared__ float tr[64 * 65];
    if (blockIdx.x < NPREP) {
        int idx = blockIdx.x * 256 + threadIdx.x;
        if (idx < 20480) {                       // Wpk1 [10][32][64]
            int k = idx >> 11, g = (idx >> 6) & 31, c = idx & 63;
            float val = 0.f;
            if (g < 25) {
                float s = 0.f;
#pragma unroll
                for (int f = 0; f < 25; ++f)
                    s = fmaf(w_spat[g * 1600 + f * 64 + c], w_time[f * 10 + k], s);
                val = s * (g1[g] * rsqrtf(v1[g] + EPS_BN));
            }
            wsz[UW1 + idx] = f2bf(val);
        } else if (idx < 40960) {                // Wpk2 [10][64][32]
            int j = idx - 20480;
            int k = j >> 11, g = (j >> 5) & 63, c = j & 31;
            float val = 0.f;
            if (g < 50 && c < 25)
                val = w2[(g * 25 + c) * 10 + k] * (g2[g] * rsqrtf(v2[g] + EPS_BN));
            wsz[UW2 + j] = f2bf(val);
        } else if (idx < 122880) {               // Wpk3 [10][128][64]
            int j = idx - 40960;
            int k = j >> 13, g = (j >> 6) & 127, c = j & 63;
            float val = 0.f;
            if (g < 100 && c < 50)
                val = w3[(g * 50 + c) * 10 + k] * (g3[g] * rsqrtf(v3[g] + EPS_BN));
            wsz[UW3 + j] = f2bf(val);
        } else if (idx < 409600) {               // Wpk4 [10][224][128]
            int j = idx - 122880;
            int k = j / 28672, r = j % 28672, g = r >> 7, c = r & 127;
            float val = 0.f;
            if (g < 200 && c < 100)
                val = w4[(g * 100 + c) * 10 + k] * (g4[g] * rsqrtf(v4[g] + EPS_BN));
            wsz[UW4 + j] = f2bf(val);
        } else if (idx < 410048) {               // biases
            int j = idx - 409600;
            if (j < 32) {
                int g = j; float val = 0.f;
                if (g < 25) {
                    float beff = 0.f;
                    for (int f = 0; f < 25; ++f) {
                        float a = 0.f;
                        for (int c = 0; c < 64; ++c) a += w_spat[g * 1600 + f * 64 + c];
                        beff = fmaf(a, b_time[f], beff);
                    }
                    float sc = g1[g] * rsqrtf(v1[g] + EPS_BN);
                    val = be1[g] - m1[g] * sc + beff * sc;
                }
                biasf[BB1 + g] = val;
            } else if (j < 96) {
                int g = j - 32; float val = 0.f;
                if (g < 50) { float sc = g2[g] * rsqrtf(v2[g] + EPS_BN); val = be2[g] - m2[g] * sc; }
                biasf[BB2 + g] = val;
            } else if (j < 224) {
                int g = j - 96; float val = 0.f;
                if (g < 100) { float sc = g3[g] * rsqrtf(v3[g] + EPS_BN); val = be3[g] - m3[g] * sc; }
                biasf[BB3 + g] = val;
            } else {
                int g = j - 224; float val = 0.f;
                if (g < 200) { float sc = g4[g] * rsqrtf(v4[g] + EPS_BN); val = be4[g] - m4[g] * sc; }
                biasf[BB4 + g] = val;
            }
        }
    } else {
        // ------- x transpose: tile (b, 64 t) -> xT[b][t][c] bf16 -------
        const int bid = blockIdx.x - NPREP;
        const int b = bid / 17, tile = bid % 17, t = threadIdx.x;
        const int t0 = tile * 64;
        const float* xb = x + b * 64000;
        for (int idx = t; idx < 1024; idx += 256) {
            int c = idx >> 4, q = idx & 15;
            int tg = t0 + 4 * q;
            float4 v = {0.f, 0.f, 0.f, 0.f};
            if (tg + 4 <= 1000) {
                v = *(const float4*)(xb + c * 1000 + tg);
            } else {
                float* pv = (float*)&v;
#pragma unroll
                for (int e = 0; e < 4; ++e)
                    if (tg + e < 1000) pv[e] = xb[c * 1000 + tg + e];
            }
            tr[c * 65 + 4 * q]     = v.x;
            tr[c * 65 + 4 * q + 1] = v.y;
            tr[c * 65 + 4 * q + 2] = v.z;
            tr[c * 65 + 4 * q + 3] = v.w;
        }
        __syncthreads();
        unsigned short* xTg = wsz + XTG_U;
        for (int idx = t; idx < 2048; idx += 256) {
            int tl = idx >> 5, cp = idx & 31;
            int tg = t0 + tl;
            unsigned int pk = 0u;
            if (tg < 1000)
                pk = (unsigned int)f2bf(tr[(2 * cp) * 65 + tl]) |
                     ((unsigned int)f2bf(tr[(2 * cp + 1) * 65 + tl]) << 16);
            if (tg < 1072)
                *(unsigned int*)&xTg[(b * 1072 + tg) * 64 + 2 * cp] = pk;
        }
    }
}

// ---------------------------------------------------------------------------
// conv_job16: 16-output-channel wave-job of MFMA conv(K=10)+bias+ELU+pool3.
// Mechanical halving of the verified conv_job (rounds 7-11): B-operand rows
// (gh*16+lm), single acc half, zb 48x20. Pool: 4 row-groups (lane>>4).
// ---------------------------------------------------------------------------
template<int CPAD, int RS, int SP, int TT, int TPC, int JMAX4,
         int GPAD, int TPOOL, int GSTORE, int NGV, int OUT_RS, bool OUT_F32,
         int KPRE>
__device__ __forceinline__ void conv_job16(
    const unsigned short* xT, const unsigned short* __restrict__ wpk,
    const float* __restrict__ bias,
    unsigned short* zout, float* zoutf, unsigned short* zbw,
    int lane, int gh, int po0) {
    const int lm = lane & 15, h8 = lane >> 4;

    f32x4 acc[TT];
#pragma unroll
    for (int i = 0; i < TT; ++i) acc[i] = (f32x4){0.f, 0.f, 0.f, 0.f};

    const int abase = lm * RS + h8 * 8;
    const unsigned short* wp = wpk + (gh * 16 + lm) * CPAD + h8 * 8;
#pragma unroll
    for (int ph = 0; ph < 10 / KPRE; ++ph) {
        short8 w0r[KPRE][SP];
#pragma unroll
        for (int kk = 0; kk < KPRE; ++kk) {
            const int k = ph * KPRE + kk;
#pragma unroll
            for (int s = 0; s < SP; ++s)
                w0r[kk][s] = *(const short8*)(wp + k * (GPAD * CPAD) + s * 32);
        }
#pragma unroll
        for (int kk = 0; kk < KPRE; ++kk) {
            const int k = ph * KPRE + kk;
#pragma unroll
            for (int s = 0; s < SP; ++s) {
#pragma unroll
                for (int tt = 0; tt < TT; ++tt) {
                    short8 a = *(const short8*)&xT[abase + (tt * 16 + k) * RS + s * 32];
                    acc[tt] = __builtin_amdgcn_mfma_f32_16x16x32_bf16(
                        a, w0r[kk][s], acc[tt], 0, 0, 0);
                }
            }
        }
    }

    const float bv0 = bias[gh * 16 + lm];
#pragma unroll
    for (int ti = 0; ti < TPC; ++ti) {
#pragma unroll
        for (int r = 0; r < 4; ++r) {
            float v0 = elu1(acc[ti][r] + bv0);
            int row = ti * 16 + 4 * h8 + r;
            zbw[row * RS2 + lm] = f2bf(v0);
        }
    }
#pragma unroll
    for (int j = 0; j < JMAX4; ++j) {
        int po = h8 + 4 * j;
        if (3 * po + 2 < TPC * 16) {
            float q0 = bf2f(zbw[(3 * po) * RS2 + lm]);
            float q1 = bf2f(zbw[(3 * po + 1) * RS2 + lm]);
            float q2 = bf2f(zbw[(3 * po + 2) * RS2 + lm]);
            float mx = fmaxf(q0, fmaxf(q1, q2));
            int poa = po0 + po;
            int ga = gh * 16 + lm;
            if (poa < TPOOL && ga < GSTORE) {
                if constexpr (OUT_F32)
                    zoutf[poa * OUT_RS + ga] = mx;
                else
                    zout[poa * OUT_RS + ga] =
                        (ga < NGV) ? f2bf(mx) : (unsigned short)0;
            }
        }
    }
}

// ---------------------------------------------------------------------------
// ks1: stage1. grid (128, 11), 256 thr = 4 waves sharing a 112-row xT tile.
// wave w: tci = 2*by + (w&1), gh = w>>1 (2 g-halves of 32-pad / 25 valid).
// ---------------------------------------------------------------------------
__global__ __launch_bounds__(256) void ks1(
    const unsigned short* __restrict__ wsu, const float* __restrict__ biasf,
    unsigned short* __restrict__ wsz) {
    __shared__ __align__(16) unsigned short xT[112 * 72];
    __shared__ __align__(16) unsigned short zb[4 * ZBW];
    const int b = blockIdx.x, by = blockIdx.y, t = threadIdx.x;
    const int lane = t & 63, wv = t >> 6;
    const int t0 = by * 96;
    const unsigned short* xTg = wsz + XTG_U + (b * 1072 + t0) * 64;
    for (int idx = t; idx < 112 * 8; idx += 256) {
        int r = idx >> 3, q = idx & 7;
        *(uint4v*)&xT[r * 72 + 8 * q] = *(const uint4v*)&xTg[r * 64 + 8 * q];
    }
    __syncthreads();
    const int tc = wv & 1, gh = wv >> 1;
    const int tci = 2 * by + tc;
    if (tci < 21) {
        conv_job16<64, 72, 2, 3, 3, 4, 32, 330, 32, 25, 32, false, 5>(
            xT + (tc * 48) * 72, wsu + UW1, biasf + BB1,
            wsz + Z1G_U + b * 330 * 32, nullptr, zb + wv * ZBW,
            lane, gh, tci * 16);
    }
}

// ---------------------------------------------------------------------------
// ks2: stage2. grid (128, 7), 256 thr = 4 waves (gh 0..3) sharing one tile.
// ---------------------------------------------------------------------------
__global__ __launch_bounds__(256) void ks2(
    const unsigned short* __restrict__ wsu, const float* __restrict__ biasf,
    unsigned short* __restrict__ wsz) {
    __shared__ __align__(16) unsigned short xT[64 * 40];
    __shared__ __align__(16) unsigned short zb[4 * ZBW];
    const int b = blockIdx.x, tci = blockIdx.y, t = threadIdx.x;
    const int lane = t & 63, wv = t >> 6;
    const int t0b = tci * 48;
    const unsigned short* z1g = wsz + Z1G_U + b * 330 * 32;
    for (int idx = t; idx < 256; idx += 256) {
        int r = idx >> 2, q = idx & 3;
        uint4v v = {0u, 0u, 0u, 0u};
        if (t0b + r < 330) v = *(const uint4v*)&z1g[(t0b + r) * 32 + 8 * q];
        *(uint4v*)&xT[r * 40 + 8 * q] = v;
    }
    __syncthreads();
    conv_job16<32, 40, 1, 3, 3, 4, 64, 107, 64, 50, 64, false, 5>(
        xT, wsu + UW2, biasf + BB2,
        wsz + Z2G_U + b * 107 * 64, nullptr, zb + wv * ZBW,
        lane, wv, tci * 16);
}

// ---------------------------------------------------------------------------
// ks3: stage3. grid (128, 2), 512 thr = 8 waves (gh 0..7) sharing one tile.
// ---------------------------------------------------------------------------
__global__ __launch_bounds__(512) void ks3(
    const unsigned short* __restrict__ wsu, const float* __restrict__ biasf,
    unsigned short* __restrict__ wsz) {
    __shared__ __align__(16) unsigned short z2t[64 * 72];
    __shared__ __align__(16) unsigned short zb[8 * ZBW];
    const int b = blockIdx.x, tci = blockIdx.y, t = threadIdx.x;
    const int lane = t & 63, wv = t >> 6;
    const int t0b = tci * 48;
    const unsigned short* z2g = wsz + Z2G_U + b * 107 * 64;
    for (int idx = t; idx < 512; idx += 512) {
        int r = idx >> 3, q = idx & 7;
        uint4v v = {0u, 0u, 0u, 0u};
        if (t0b + r < 107) v = *(const uint4v*)&z2g[(t0b + r) * 64 + 8 * q];
        *(uint4v*)&z2t[r * 72 + 8 * q] = v;
    }
    __syncthreads();
    conv_job16<64, 72, 2, 3, 3, 4, 128, 32, 128, 100, 136, false, 5>(
        z2t, wsu + UW3, biasf + BB3,
        wsz + Z3G_U + b * 44 * 136, nullptr, zb + wv * ZBW,
        lane, wv, tci * 16);
}

// ---------------------------------------------------------------------------
// ks4: stage4. grid (128, 13), 64 thr = 1 wave = 1 g-half (g 0..207, 200 valid).
// Stages z3 (rows>=32 zeroed), writes z4 f32 [b][7][200].
// ---------------------------------------------------------------------------
__global__ __launch_bounds__(64) void ks4(
    const unsigned short* __restrict__ wsu, const float* __restrict__ biasf,
    unsigned short* __restrict__ wsz, float* __restrict__ z4g) {
    __shared__ __align__(16) unsigned short z3t[44 * 136];
    __shared__ __align__(16) unsigned short zb[ZBW];
    const int b = blockIdx.x, gh = blockIdx.y, lane = threadIdx.x;
    const unsigned short* z3g = wsz + Z3G_U + b * 44 * 136;
    for (int idx = lane; idx < 748; idx += 64) {
        int r = idx / 17, q = idx % 17;
        uint4v v = {0u, 0u, 0u, 0u};
        if (r < 32) v = *(const uint4v*)&z3g[r * 136 + 8 * q];
        *(uint4v*)&z3t[r * 136 + 8 * q] = v;
    }
    __syncthreads();
    conv_job16<128, 136, 4, 2, 2, 2, 224, 7, 200, 200, 200, true, 5>(
        z3t, wsu + UW4, biasf + BB4,
        nullptr, z4g + b * 1400, zb, lane, gh, 0);
}

// ---------------------------------------------------------------------------
// kh: classifier conv + per-cluster expert head. 128 blocks x 256 threads.
// ---------------------------------------------------------------------------
__global__ __launch_bounds__(256) void kh(
    const float* __restrict__ z4g,
    const float* __restrict__ w_cls, const float* __restrict__ b_cls,
    const int* __restrict__ cid,
    const float* __restrict__ hW1, const float* __restrict__ hb1,
    const float* __restrict__ hW2, const float* __restrict__ hb2,
    const float* __restrict__ hg, const float* __restrict__ hbe,
    const float* __restrict__ hm, const float* __restrict__ hv,
    float* __restrict__ out) {
    __shared__ float z4f[1400];
    __shared__ float feats[4];
    __shared__ float h1s[512];
    const int b = blockIdx.x, t = threadIdx.x;
    for (int i = t; i < 1400; i += 256) z4f[i] = z4g[b * 1400 + i];
    __syncthreads();

    const int wv = t >> 6, lane = t & 63;
    {
        float p = 0.f;
        for (int i = lane; i < 1400; i += 64) {
            int po = i / 200, g = i - po * 200;
            p = fmaf(z4f[i], w_cls[wv * 1400 + g * 7 + po], p);
        }
        p = warp_sum(p);
        if (lane == 0) feats[wv] = p + b_cls[wv];
    }
    __syncthreads();

    const int c = cid[b];
    const float f0 = feats[0], f1 = feats[1], f2 = feats[2], f3 = feats[3];
    for (int h = t; h < 512; h += 256) {
        const float* w1 = &hW1[(c * 512 + h) * 4];
        float v = f0 * w1[0] + f1 * w1[1] + f2 * w1[2] + f3 * w1[3] + hb1[c * 512 + h];
        float sc = hg[c * 512 + h] * rsqrtf(hv[c * 512 + h] + EPS_BN);
        v = (v - hm[c * 512 + h]) * sc + hbe[c * 512 + h];
        h1s[h] = fmaxf(v, 0.f);
    }
    __syncthreads();
    {
        float p = 0.f;
        for (int i = lane; i < 512; i += 64)
            p = fmaf(h1s[i], hW2[(c * 4 + wv) * 512 + i], p);
        p = warp_sum(p);
        if (lane == 0) out[b * 4 + wv] = p + hb2[c * 4 + wv];
    }
}

// ---------------------------------------------------------------------------
extern "C" void kernel_launch(void* const* d_in, const int* in_sizes, int n_in,
                              void* d_out, int out_size, void* d_ws, size_t ws_size,
                              hipStream_t stream) {
    const float* x      = (const float*)d_in[0];
    const int*   cid    = (const int*)d_in[1];
    const float* w_time = (const float*)d_in[2];
    const float* b_time = (const float*)d_in[3];
    const float* w_spat = (const float*)d_in[4];
    const float* w2     = (const float*)d_in[5];
    const float* w3     = (const float*)d_in[6];
    const float* w4     = (const float*)d_in[7];
    const float* w_cls  = (const float*)d_in[8];
    const float* b_cls  = (const float*)d_in[9];
    const float* hW1    = (const float*)d_in[10];
    const float* hb1    = (const float*)d_in[11];
    const float* hW2    = (const float*)d_in[12];
    const float* hb2    = (const float*)d_in[13];
    const float* hg     = (const float*)d_in[14];
    const float* hbe    = (const float*)d_in[15];
    const float* hm     = (const float*)d_in[16];
    const float* hv     = (const float*)d_in[17];
    const float* g1  = (const float*)d_in[18];
    const float* be1 = (const float*)d_in[19];
    const float* m1  = (const float*)d_in[20];
    const float* v1  = (const float*)d_in[21];
    const float* g2  = (const float*)d_in[22];
    const float* be2 = (const float*)d_in[23];
    const float* m2  = (const float*)d_in[24];
    const float* v2  = (const float*)d_in[25];
    const float* g3  = (const float*)d_in[26];
    const float* be3 = (const float*)d_in[27];
    const float* m3  = (const float*)d_in[28];
    const float* v3  = (const float*)d_in[29];
    const float* g4  = (const float*)d_in[30];
    const float* be4 = (const float*)d_in[31];
    const float* m4  = (const float*)d_in[32];
    const float* v4  = (const float*)d_in[33];

    unsigned short* wsz = (unsigned short*)d_ws;
    float* biasf = (float*)((char*)d_ws + 819200);
    float* z4g   = (float*)((char*)d_ws + Z4G_BYTE);
    float* out = (float*)d_out;

    kprep_tr<<<NPREP + 128 * 17, 256, 0, stream>>>(
        x, w_time, b_time, w_spat, w2, w3, w4,
        g1, be1, m1, v1, g2, be2, m2, v2, g3, be3, m3, v3, g4, be4, m4, v4,
        wsz, biasf);

    ks1<<<dim3(128, 11), 256, 0, stream>>>(wsz, biasf, wsz);
    ks2<<<dim3(128, 7), 256, 0, stream>>>(wsz, biasf, wsz);
    ks3<<<dim3(128, 2), 512, 0, stream>>>(wsz, biasf, wsz);
    ks4<<<dim3(128, 13), 64, 0, stream>>>(wsz, biasf, wsz, z4g);
    kh<<<128, 256, 0, stream>>>(z4g, w_cls, b_cls, cid, hW1, hb1, hW2, hb2,
                                hg, hbe, hm, hv, out);
}

// Round 13
// 92.566 us; speedup vs baseline: 1.3170x; 1.0167x over previous
//
#include <hip/hip_runtime.h>
#include <math.h>

#define EPS_BN 1e-5f

typedef __attribute__((ext_vector_type(8))) short short8;
typedef __attribute__((ext_vector_type(4))) float f32x4;
typedef __attribute__((ext_vector_type(4))) unsigned int uint4v;

__device__ __forceinline__ unsigned short f2bf(float f) {
    unsigned int u = __float_as_uint(f);
    u = (u + 0x7fffu + ((u >> 16) & 1u)) >> 16;
    return (unsigned short)u;
}
__device__ __forceinline__ float bf2f(unsigned short s) {
    return __uint_as_float(((unsigned int)s) << 16);
}
__device__ __forceinline__ float elu1(float y) { return y > 0.f ? y : expm1f(y); }
__device__ __forceinline__ float warp_sum(float v) {
    for (int off = 32; off > 0; off >>= 1) v += __shfl_down(v, off);
    return v;
}

// ---------------- workspace layout ----------------
#define UW1 0        // [10][32][64]   20480
#define UW2 20480    // [10][64][32]   20480
#define UW3 40960    // [10][128][64]  81920
#define UW4 122880   // [10][224][128] 286720 -> ends 409600 ush (819200 B)
#define BB1 0
#define BB2 32
#define BB3 96
#define BB4 224
#define XTG_U 410496    // xT  [128][1072][64]  (byte 820992)
#define Z1G_U 9192320   // z1  [128][330][32]
#define Z2G_U 10544000  // z2  [128][107][64]
#define Z3G_U 11420544  // z3  [128][44][136]
#define Z4G_BYTE 24372992  // z4 f32 [128][7][200]

#define NPREP 1602
#define RS2 20          // zb stride for 16-g jobs (16 cols + 4 pad)
#define ZBW (48 * RS2)  // 960 ush = 1920 B per wave

// ---------------------------------------------------------------------------
// kprep_tr: blocks [0,NPREP) = BN-folded bf16 weight prep (verified round 3);
//           blocks >= NPREP  = tiled x transpose -> xT bf16 [b][t][c]
//           (coalesced reads, padded-LDS bounce, coalesced writes). R7-exact.
// ---------------------------------------------------------------------------
__global__ __launch_bounds__(256) void kprep_tr(
    const float* __restrict__ x,
    const float* __restrict__ w_time, const float* __restrict__ b_time,
    const float* __restrict__ w_spat,
    const float* __restrict__ w2, const float* __restrict__ w3,
    const float* __restrict__ w4,
    const float* __restrict__ g1, const float* __restrict__ be1,
    const float* __restrict__ m1, const float* __restrict__ v1,
    const float* __restrict__ g2, const float* __restrict__ be2,
    const float* __restrict__ m2, const float* __restrict__ v2,
    const float* __restrict__ g3, const float* __restrict__ be3,
    const float* __restrict__ m3, const float* __restrict__ v3,
    const float* __restrict__ g4, const float* __restrict__ be4,
    const float* __restrict__ m4, const float* __restrict__ v4,
    unsigned short* __restrict__ wsz, float* __restrict__ biasf) {
    __shared__ float tr[64 * 65];
    if (blockIdx.x < NPREP) {
        int idx = blockIdx.x * 256 + threadIdx.x;
        if (idx < 20480) {                       // Wpk1 [10][32][64]
            int k = idx >> 11, g = (idx >> 6) & 31, c = idx & 63;
            float val = 0.f;
            if (g < 25) {
                float s = 0.f;
#pragma unroll
                for (int f = 0; f < 25; ++f)
                    s = fmaf(w_spat[g * 1600 + f * 64 + c], w_time[f * 10 + k], s);
                val = s * (g1[g] * rsqrtf(v1[g] + EPS_BN));
            }
            wsz[UW1 + idx] = f2bf(val);
        } else if (idx < 40960) {                // Wpk2 [10][64][32]
            int j = idx - 20480;
            int k = j >> 11, g = (j >> 5) & 63, c = j & 31;
            float val = 0.f;
            if (g < 50 && c < 25)
                val = w2[(g * 25 + c) * 10 + k] * (g2[g] * rsqrtf(v2[g] + EPS_BN));
            wsz[UW2 + j] = f2bf(val);
        } else if (idx < 122880) {               // Wpk3 [10][128][64]
            int j = idx - 40960;
            int k = j >> 13, g = (j >> 6) & 127, c = j & 63;
            float val = 0.f;
            if (g < 100 && c < 50)
                val = w3[(g * 50 + c) * 10 + k] * (g3[g] * rsqrtf(v3[g] + EPS_BN));
            wsz[UW3 + j] = f2bf(val);
        } else if (idx < 409600) {               // Wpk4 [10][224][128]
            int j = idx - 122880;
            int k = j / 28672, r = j % 28672, g = r >> 7, c = r & 127;
            float val = 0.f;
            if (g < 200 && c < 100)
                val = w4[(g * 100 + c) * 10 + k] * (g4[g] * rsqrtf(v4[g] + EPS_BN));
            wsz[UW4 + j] = f2bf(val);
        } else if (idx < 410048) {               // biases
            int j = idx - 409600;
            if (j < 32) {
                int g = j; float val = 0.f;
                if (g < 25) {
                    float beff = 0.f;
                    for (int f = 0; f < 25; ++f) {
                        float a = 0.f;
                        for (int c = 0; c < 64; ++c) a += w_spat[g * 1600 + f * 64 + c];
                        beff = fmaf(a, b_time[f], beff);
                    }
                    float sc = g1[g] * rsqrtf(v1[g] + EPS_BN);
                    val = be1[g] - m1[g] * sc + beff * sc;
                }
                biasf[BB1 + g] = val;
            } else if (j < 96) {
                int g = j - 32; float val = 0.f;
                if (g < 50) { float sc = g2[g] * rsqrtf(v2[g] + EPS_BN); val = be2[g] - m2[g] * sc; }
                biasf[BB2 + g] = val;
            } else if (j < 224) {
                int g = j - 96; float val = 0.f;
                if (g < 100) { float sc = g3[g] * rsqrtf(v3[g] + EPS_BN); val = be3[g] - m3[g] * sc; }
                biasf[BB3 + g] = val;
            } else {
                int g = j - 224; float val = 0.f;
                if (g < 200) { float sc = g4[g] * rsqrtf(v4[g] + EPS_BN); val = be4[g] - m4[g] * sc; }
                biasf[BB4 + g] = val;
            }
        }
    } else {
        // ------- x transpose: tile (b, 64 t) -> xT[b][t][c] bf16 -------
        const int bid = blockIdx.x - NPREP;
        const int b = bid / 17, tile = bid % 17, t = threadIdx.x;
        const int t0 = tile * 64;
        const float* xb = x + b * 64000;
        for (int idx = t; idx < 1024; idx += 256) {
            int c = idx >> 4, q = idx & 15;
            int tg = t0 + 4 * q;
            float4 v = {0.f, 0.f, 0.f, 0.f};
            if (tg + 4 <= 1000) {
                v = *(const float4*)(xb + c * 1000 + tg);
            } else {
                float* pv = (float*)&v;
#pragma unroll
                for (int e = 0; e < 4; ++e)
                    if (tg + e < 1000) pv[e] = xb[c * 1000 + tg + e];
            }
            tr[c * 65 + 4 * q]     = v.x;
            tr[c * 65 + 4 * q + 1] = v.y;
            tr[c * 65 + 4 * q + 2] = v.z;
            tr[c * 65 + 4 * q + 3] = v.w;
        }
        __syncthreads();
        unsigned short* xTg = wsz + XTG_U;
        for (int idx = t; idx < 2048; idx += 256) {
            int tl = idx >> 5, cp = idx & 31;
            int tg = t0 + tl;
            unsigned int pk = 0u;
            if (tg < 1000)
                pk = (unsigned int)f2bf(tr[(2 * cp) * 65 + tl]) |
                     ((unsigned int)f2bf(tr[(2 * cp + 1) * 65 + tl]) << 16);
            if (tg < 1072)
                *(unsigned int*)&xTg[(b * 1072 + tg) * 64 + 2 * cp] = pk;
        }
    }
}

// ---------------------------------------------------------------------------
// conv_job16: 16-output-channel wave-job of MFMA conv(K=10)+bias+ELU+pool3.
// (validated round 12: B rows gh*16+lm, single acc half, zb 48x20.)
// ---------------------------------------------------------------------------
template<int CPAD, int RS, int SP, int TT, int TPC, int JMAX4,
         int GPAD, int TPOOL, int GSTORE, int NGV, int OUT_RS, bool OUT_F32,
         int KPRE>
__device__ __forceinline__ void conv_job16(
    const unsigned short* xT, const unsigned short* __restrict__ wpk,
    const float* __restrict__ bias,
    unsigned short* zout, float* zoutf, unsigned short* zbw,
    int lane, int gh, int po0) {
    const int lm = lane & 15, h8 = lane >> 4;

    f32x4 acc[TT];
#pragma unroll
    for (int i = 0; i < TT; ++i) acc[i] = (f32x4){0.f, 0.f, 0.f, 0.f};

    const int abase = lm * RS + h8 * 8;
    const unsigned short* wp = wpk + (gh * 16 + lm) * CPAD + h8 * 8;
#pragma unroll
    for (int ph = 0; ph < 10 / KPRE; ++ph) {
        short8 w0r[KPRE][SP];
#pragma unroll
        for (int kk = 0; kk < KPRE; ++kk) {
            const int k = ph * KPRE + kk;
#pragma unroll
            for (int s = 0; s < SP; ++s)
                w0r[kk][s] = *(const short8*)(wp + k * (GPAD * CPAD) + s * 32);
        }
#pragma unroll
        for (int kk = 0; kk < KPRE; ++kk) {
            const int k = ph * KPRE + kk;
#pragma unroll
            for (int s = 0; s < SP; ++s) {
#pragma unroll
                for (int tt = 0; tt < TT; ++tt) {
                    short8 a = *(const short8*)&xT[abase + (tt * 16 + k) * RS + s * 32];
                    acc[tt] = __builtin_amdgcn_mfma_f32_16x16x32_bf16(
                        a, w0r[kk][s], acc[tt], 0, 0, 0);
                }
            }
        }
    }

    const float bv0 = bias[gh * 16 + lm];
#pragma unroll
    for (int ti = 0; ti < TPC; ++ti) {
#pragma unroll
        for (int r = 0; r < 4; ++r) {
            float v0 = elu1(acc[ti][r] + bv0);
            int row = ti * 16 + 4 * h8 + r;
            zbw[row * RS2 + lm] = f2bf(v0);
        }
    }
#pragma unroll
    for (int j = 0; j < JMAX4; ++j) {
        int po = h8 + 4 * j;
        if (3 * po + 2 < TPC * 16) {
            float q0 = bf2f(zbw[(3 * po) * RS2 + lm]);
            float q1 = bf2f(zbw[(3 * po + 1) * RS2 + lm]);
            float q2 = bf2f(zbw[(3 * po + 2) * RS2 + lm]);
            float mx = fmaxf(q0, fmaxf(q1, q2));
            int poa = po0 + po;
            int ga = gh * 16 + lm;
            if (poa < TPOOL && ga < GSTORE) {
                if constexpr (OUT_F32)
                    zoutf[poa * OUT_RS + ga] = mx;
                else
                    zout[poa * OUT_RS + ga] =
                        (ga < NGV) ? f2bf(mx) : (unsigned short)0;
            }
        }
    }
}

// ---------------------------------------------------------------------------
// ks1: stage1. grid (128, 11), 256 thr = 4 waves sharing a 112-row xT tile.
// wave w: tci = 2*by + (w&1), gh = w>>1 (2 g-halves of 32-pad / 25 valid).
// ---------------------------------------------------------------------------
__global__ __launch_bounds__(256) void ks1(
    const unsigned short* __restrict__ wsu, const float* __restrict__ biasf,
    unsigned short* __restrict__ wsz) {
    __shared__ __align__(16) unsigned short xT[112 * 72];
    __shared__ __align__(16) unsigned short zb[4 * ZBW];
    const int b = blockIdx.x, by = blockIdx.y, t = threadIdx.x;
    const int lane = t & 63, wv = t >> 6;
    const int t0 = by * 96;
    const unsigned short* xTg = wsz + XTG_U + (b * 1072 + t0) * 64;
    for (int idx = t; idx < 112 * 8; idx += 256) {
        int r = idx >> 3, q = idx & 7;
        *(uint4v*)&xT[r * 72 + 8 * q] = *(const uint4v*)&xTg[r * 64 + 8 * q];
    }
    __syncthreads();
    const int tc = wv & 1, gh = wv >> 1;
    const int tci = 2 * by + tc;
    if (tci < 21) {
        conv_job16<64, 72, 2, 3, 3, 4, 32, 330, 32, 25, 32, false, 5>(
            xT + (tc * 48) * 72, wsu + UW1, biasf + BB1,
            wsz + Z1G_U + b * 330 * 32, nullptr, zb + wv * ZBW,
            lane, gh, tci * 16);
    }
}

// ---------------------------------------------------------------------------
// ks2: stage2. grid (128, 7), 256 thr = 4 waves (gh 0..3) sharing one tile.
// ---------------------------------------------------------------------------
__global__ __launch_bounds__(256) void ks2(
    const unsigned short* __restrict__ wsu, const float* __restrict__ biasf,
    unsigned short* __restrict__ wsz) {
    __shared__ __align__(16) unsigned short xT[64 * 40];
    __shared__ __align__(16) unsigned short zb[4 * ZBW];
    const int b = blockIdx.x, tci = blockIdx.y, t = threadIdx.x;
    const int lane = t & 63, wv = t >> 6;
    const int t0b = tci * 48;
    const unsigned short* z1g = wsz + Z1G_U + b * 330 * 32;
    for (int idx = t; idx < 256; idx += 256) {
        int r = idx >> 2, q = idx & 3;
        uint4v v = {0u, 0u, 0u, 0u};
        if (t0b + r < 330) v = *(const uint4v*)&z1g[(t0b + r) * 32 + 8 * q];
        *(uint4v*)&xT[r * 40 + 8 * q] = v;
    }
    __syncthreads();
    conv_job16<32, 40, 1, 3, 3, 4, 64, 107, 64, 50, 64, false, 5>(
        xT, wsu + UW2, biasf + BB2,
        wsz + Z2G_U + b * 107 * 64, nullptr, zb + wv * ZBW,
        lane, wv, tci * 16);
}

// ---------------------------------------------------------------------------
// ks3: stage3. grid (128, 4), 256 thr = 4 waves. y: tci = y&1, gh-quad = y>>1.
// (Same 2048 wave-jobs as round 12, but 512 blocks for better distribution
// and 16.8 KB LDS/block.)
// ---------------------------------------------------------------------------
__global__ __launch_bounds__(256) void ks3(
    const unsigned short* __restrict__ wsu, const float* __restrict__ biasf,
    unsigned short* __restrict__ wsz) {
    __shared__ __align__(16) unsigned short z2t[64 * 72];
    __shared__ __align__(16) unsigned short zb[4 * ZBW];
    const int b = blockIdx.x, y = blockIdx.y, t = threadIdx.x;
    const int lane = t & 63, wv = t >> 6;
    const int tci = y & 1, gq = y >> 1;
    const int t0b = tci * 48;
    const unsigned short* z2g = wsz + Z2G_U + b * 107 * 64;
    for (int idx = t; idx < 512; idx += 256) {
        int r = idx >> 3, q = idx & 7;
        uint4v v = {0u, 0u, 0u, 0u};
        if (t0b + r < 107) v = *(const uint4v*)&z2g[(t0b + r) * 64 + 8 * q];
        *(uint4v*)&z2t[r * 72 + 8 * q] = v;
    }
    __syncthreads();
    conv_job16<64, 72, 2, 3, 3, 4, 128, 32, 128, 100, 136, false, 5>(
        z2t, wsu + UW3, biasf + BB3,
        wsz + Z3G_U + b * 44 * 136, nullptr, zb + wv * ZBW,
        lane, gq * 4 + wv, tci * 16);
}

// ---------------------------------------------------------------------------
// ks4: stage4. grid (128, 4), 256 thr = 4 waves sharing one z3 tile.
// wave w: gh = y*4 + w (0..15; jobs >=13 idle). Writes z4 f32 [b][7][200].
// ---------------------------------------------------------------------------
__global__ __launch_bounds__(256) void ks4(
    const unsigned short* __restrict__ wsu, const float* __restrict__ biasf,
    unsigned short* __restrict__ wsz, float* __restrict__ z4g) {
    __shared__ __align__(16) unsigned short z3t[44 * 136];
    __shared__ __align__(16) unsigned short zb[4 * ZBW];
    const int b = blockIdx.x, y = blockIdx.y, t = threadIdx.x;
    const int lane = t & 63, wv = t >> 6;
    const unsigned short* z3g = wsz + Z3G_U + b * 44 * 136;
    for (int idx = t; idx < 748; idx += 256) {
        int r = idx / 17, q = idx % 17;
        uint4v v = {0u, 0u, 0u, 0u};
        if (r < 32) v = *(const uint4v*)&z3g[r * 136 + 8 * q];
        *(uint4v*)&z3t[r * 136 + 8 * q] = v;
    }
    __syncthreads();
    const int gh = y * 4 + wv;
    if (gh < 13) {
        conv_job16<128, 136, 4, 2, 2, 2, 224, 7, 200, 200, 200, true, 5>(
            z3t, wsu + UW4, biasf + BB4,
            nullptr, z4g + b * 1400, zb + wv * ZBW, lane, gh, 0);
    }
}

// ---------------------------------------------------------------------------
// kh: classifier conv + per-cluster expert head. 128 blocks x 256 threads.
// ---------------------------------------------------------------------------
__global__ __launch_bounds__(256) void kh(
    const float* __restrict__ z4g,
    const float* __restrict__ w_cls, const float* __restrict__ b_cls,
    const int* __restrict__ cid,
    const float* __restrict__ hW1, const float* __restrict__ hb1,
    const float* __restrict__ hW2, const float* __restrict__ hb2,
    const float* __restrict__ hg, const float* __restrict__ hbe,
    const float* __restrict__ hm, const float* __restrict__ hv,
    float* __restrict__ out) {
    __shared__ float z4f[1400];
    __shared__ float feats[4];
    __shared__ float h1s[512];
    const int b = blockIdx.x, t = threadIdx.x;
    for (int i = t; i < 1400; i += 256) z4f[i] = z4g[b * 1400 + i];
    __syncthreads();

    const int wv = t >> 6, lane = t & 63;
    {
        float p = 0.f;
        for (int i = lane; i < 1400; i += 64) {
            int po = i / 200, g = i - po * 200;
            p = fmaf(z4f[i], w_cls[wv * 1400 + g * 7 + po], p);
        }
        p = warp_sum(p);
        if (lane == 0) feats[wv] = p + b_cls[wv];
    }
    __syncthreads();

    const int c = cid[b];
    const float f0 = feats[0], f1 = feats[1], f2 = feats[2], f3 = feats[3];
    for (int h = t; h < 512; h += 256) {
        const float* w1 = &hW1[(c * 512 + h) * 4];
        float v = f0 * w1[0] + f1 * w1[1] + f2 * w1[2] + f3 * w1[3] + hb1[c * 512 + h];
        float sc = hg[c * 512 + h] * rsqrtf(hv[c * 512 + h] + EPS_BN);
        v = (v - hm[c * 512 + h]) * sc + hbe[c * 512 + h];
        h1s[h] = fmaxf(v, 0.f);
    }
    __syncthreads();
    {
        float p = 0.f;
        for (int i = lane; i < 512; i += 64)
            p = fmaf(h1s[i], hW2[(c * 4 + wv) * 512 + i], p);
        p = warp_sum(p);
        if (lane == 0) out[b * 4 + wv] = p + hb2[c * 4 + wv];
    }
}

// ---------------------------------------------------------------------------
extern "C" void kernel_launch(void* const* d_in, const int* in_sizes, int n_in,
                              void* d_out, int out_size, void* d_ws, size_t ws_size,
                              hipStream_t stream) {
    const float* x      = (const float*)d_in[0];
    const int*   cid    = (const int*)d_in[1];
    const float* w_time = (const float*)d_in[2];
    const float* b_time = (const float*)d_in[3];
    const float* w_spat = (const float*)d_in[4];
    const float* w2     = (const float*)d_in[5];
    const float* w3     = (const float*)d_in[6];
    const float* w4     = (const float*)d_in[7];
    const float* w_cls  = (const float*)d_in[8];
    const float* b_cls  = (const float*)d_in[9];
    const float* hW1    = (const float*)d_in[10];
    const float* hb1    = (const float*)d_in[11];
    const float* hW2    = (const float*)d_in[12];
    const float* hb2    = (const float*)d_in[13];
    const float* hg     = (const float*)d_in[14];
    const float* hbe    = (const float*)d_in[15];
    const float* hm     = (const float*)d_in[16];
    const float* hv     = (const float*)d_in[17];
    const float* g1  = (const float*)d_in[18];
    const float* be1 = (const float*)d_in[19];
    const float* m1  = (const float*)d_in[20];
    const float* v1  = (const float*)d_in[21];
    const float* g2  = (const float*)d_in[22];
    const float* be2 = (const float*)d_in[23];
    const float* m2  = (const float*)d_in[24];
    const float* v2  = (const float*)d_in[25];
    const float* g3  = (const float*)d_in[26];
    const float* be3 = (const float*)d_in[27];
    const float* m3  = (const float*)d_in[28];
    const float* v3  = (const float*)d_in[29];
    const float* g4  = (const float*)d_in[30];
    const float* be4 = (const float*)d_in[31];
    const float* m4  = (const float*)d_in[32];
    const float* v4  = (const float*)d_in[33];

    unsigned short* wsz = (unsigned short*)d_ws;
    float* biasf = (float*)((char*)d_ws + 819200);
    float* z4g   = (float*)((char*)d_ws + Z4G_BYTE);
    float* out = (float*)d_out;

    kprep_tr<<<NPREP + 128 * 17, 256, 0, stream>>>(
        x, w_time, b_time, w_spat, w2, w3, w4,
        g1, be1, m1, v1, g2, be2, m2, v2, g3, be3, m3, v3, g4, be4, m4, v4,
        wsz, biasf);

    ks1<<<dim3(128, 11), 256, 0, stream>>>(wsz, biasf, wsz);
    ks2<<<dim3(128, 7), 256, 0, stream>>>(wsz, biasf, wsz);
    ks3<<<dim3(128, 4), 256, 0, stream>>>(wsz, biasf, wsz);
    ks4<<<dim3(128, 4), 256, 0, stream>>>(wsz, biasf, wsz, z4g);
    kh<<<128, 256, 0, stream>>>(z4g, w_cls, b_cls, cid, hW1, hb1, hW2, hb2,
                                hg, hbe, hm, hv, out);
}